// Round 9
// baseline (372.915 us; speedup 1.0000x reference)
//
#include <hip/hip_runtime.h>
#include <stdint.h>
#include <stddef.h>

typedef __bf16 bf16;
typedef __bf16 bf16x4 __attribute__((ext_vector_type(4)));
typedef __bf16 bf16x8 __attribute__((ext_vector_type(8)));
typedef float f32x4 __attribute__((ext_vector_type(4)));

#define MFMA(a, b, c) __builtin_amdgcn_mfma_f32_16x16x32_bf16(a, b, c, 0, 0, 0)

static constexpr int kB = 4, kN = 4096, kC = 1024, kH = 16, kD = 64;
static constexpr int kM = kB * kN;   // 16384 token rows
static constexpr int kK = 1024;      // contraction dim for both GEMMs
static constexpr int kQKVN = 3072;

// async 16B global->LDS (direct-to-LDS DMA; dest = wave-uniform base + lane*16)
__device__ __forceinline__ void cp16(const void* g, void* l) {
  __builtin_amdgcn_global_load_lds(
      (const __attribute__((address_space(1))) void*)g,
      (__attribute__((address_space(3))) void*)l, 16, 0, 0);
}

// fp32 -> bf16 elementwise convert, 4 elems/thread
__global__ __launch_bounds__(256) void cvt_bf16(const float* __restrict__ src,
                                                bf16* __restrict__ dst, int n4) {
  const int i = blockIdx.x * 256 + threadIdx.x;
  if (i < n4) {
    const float4 v = ((const float4*)src)[i];
    bf16x4 o = {(bf16)v.x, (bf16)v.y, (bf16)v.z, (bf16)v.w};
    *(bf16x4*)&dst[4 * i] = o;
  }
}

// rope on 8 consecutive d-elements (4 aligned pairs)
__device__ __forceinline__ bf16x8 rope8(bf16x8 t, bf16x8 f) {
  bf16x8 o;
#pragma unroll
  for (int p = 0; p < 4; ++p) {
    float t0 = (float)t[2 * p], t1 = (float)t[2 * p + 1];
    float f0 = (float)f[2 * p], f1 = (float)f[2 * p + 1];
    o[2 * p]     = (bf16)(t0 * f0 - t1 * f1);
    o[2 * p + 1] = (bf16)(t1 * f0 + t0 * f1);
  }
  return o;
}

// C[m][n] = sum_k A[m][k] * Bw[n][k] (+ bias[n]).  A: kM x kK, Bw: NOUT x kK (bf16 row-major).
// m201-style 4-phase schedule, BK=64, ring-2, k-step-planed LDS (0 conflicts, r8: 121us).
// Unchanged from round 8; now launched as per-slab dispatches (grid 4 x 64 = 256 blocks
// = exactly 1 block/CU/round) so the attn/proj kernels surface in the profile top-5.
template <int NOUT, bool BIAS, typename OutT>
__global__ __launch_bounds__(512, 2) void gemm_bt(const bf16* __restrict__ A,
                                                  const bf16* __restrict__ Bw,
                                                  const float* __restrict__ bias,
                                                  OutT* __restrict__ Cout) {
  __shared__ unsigned short As[2][2][8192];  // [buf][half][(ks*128+row)*32 + slot*8 + e]
  __shared__ unsigned short Bs[2][2][8192];
  const int tid = threadIdx.x;
  const int wave = tid >> 6, lane = tid & 63;
  const int q4 = lane >> 4, l16 = lane & 15;
  const int wr = wave >> 2, wc = wave & 3;

  const int nwg = gridDim.x * gridDim.y;
  int bid = blockIdx.y * gridDim.x + blockIdx.x;
  bid = (bid & 7) * (nwg >> 3) + (bid >> 3);
  const int bx = bid % gridDim.x, by = bid / gridDim.x;
  const int n0 = bx * 256, m0 = by * 256;

  constexpr int NT = kK / 64;  // 16 K-tiles of K=64

  f32x4 acc[8][4] = {};

  auto stageA = [&](int kt, int half) {
    const int buf = kt & 1;
#pragma unroll
    for (int i = 0; i < 2; ++i) {
      const int c = i * 512 + tid;  // 0..1023; LDS dest = c*16B (linear)
      const int ks = c >> 9, row = (c >> 2) & 127, s = c & 3;
      const int kb = ks * 4 + (s ^ ((row >> 1) & 3));
      cp16(A + (size_t)(m0 + half * 128 + row) * kK + kt * 64 + kb * 8,
           &As[buf][half][c * 8]);
    }
  };
  auto stageB = [&](int kt, int half) {
    const int buf = kt & 1;
#pragma unroll
    for (int i = 0; i < 2; ++i) {
      const int c = i * 512 + tid;
      const int ks = c >> 9, row = (c >> 2) & 127, s = c & 3;
      const int kb = ks * 4 + (s ^ ((row >> 1) & 3));
      cp16(Bw + (size_t)(n0 + half * 128 + row) * kK + kt * 64 + kb * 8,
           &Bs[buf][half][c * 8]);
    }
  };

  // prologue: A(0),B(0),B(1); confirm A(0)+B(0) (leave B(1)'s 4 loads in flight)
  stageA(0, 0); stageA(0, 1); stageB(0, 0); stageB(0, 1); stageB(1, 0); stageB(1, 1);
  asm volatile("s_waitcnt vmcnt(4)\n\ts_barrier" ::: "memory");

  const int s8 = (q4 ^ ((l16 >> 1) & 3)) * 8;  // lane-constant read swizzle (shorts)
  const int brow = (wc & 1) * 64;              // row base within B half

  for (int t = 0; t < NT; ++t) {
    const int rb = t & 1;
    const unsigned short* Ab = &As[rb][wr][0];
    const unsigned short* Bb = &Bs[rb][wc >> 1][0];
    bf16x8 a[4][2], b[4][2];

    // ---- phase 0: a[0-3] + b[0-1]; stage A(t+1) half0; MFMA (i0-3, j0-1)
#pragma unroll
    for (int i = 0; i < 4; ++i) {
      const int row = i * 16 + l16;
      a[i][0] = *(const bf16x8*)&Ab[row * 32 + s8];
      a[i][1] = *(const bf16x8*)&Ab[(128 + row) * 32 + s8];
    }
#pragma unroll
    for (int j = 0; j < 2; ++j) {
      const int row = brow + j * 16 + l16;
      b[j][0] = *(const bf16x8*)&Bb[row * 32 + s8];
      b[j][1] = *(const bf16x8*)&Bb[(128 + row) * 32 + s8];
    }
    if (t + 1 < NT) stageA(t + 1, 0);
    asm volatile("s_barrier" ::: "memory");
    __builtin_amdgcn_s_setprio(1);
#pragma unroll
    for (int i = 0; i < 4; ++i)
#pragma unroll
      for (int j = 0; j < 2; ++j)
#pragma unroll
        for (int ks = 0; ks < 2; ++ks)
          acc[i][j] = MFMA(a[i][ks], b[j][ks], acc[i][j]);
    __builtin_amdgcn_s_setprio(0);
    asm volatile("s_barrier" ::: "memory");

    // ---- phase 1: b[2-3]; stage A(t+1) half1; MFMA (i0-3, j2-3)
#pragma unroll
    for (int j = 2; j < 4; ++j) {
      const int row = brow + j * 16 + l16;
      b[j][0] = *(const bf16x8*)&Bb[row * 32 + s8];
      b[j][1] = *(const bf16x8*)&Bb[(128 + row) * 32 + s8];
    }
    if (t + 1 < NT) stageA(t + 1, 1);
    asm volatile("s_barrier" ::: "memory");
    __builtin_amdgcn_s_setprio(1);
#pragma unroll
    for (int i = 0; i < 4; ++i)
#pragma unroll
      for (int j = 2; j < 4; ++j)
#pragma unroll
        for (int ks = 0; ks < 2; ++ks)
          acc[i][j] = MFMA(a[i][ks], b[j][ks], acc[i][j]);
    __builtin_amdgcn_s_setprio(0);
    asm volatile("s_barrier" ::: "memory");

    // ---- phase 2: a[4-7] (reuse regs); stage B(t+2) half0; MFMA (i4-7, j0-1)
#pragma unroll
    for (int i = 0; i < 4; ++i) {
      const int row = (4 + i) * 16 + l16;
      a[i][0] = *(const bf16x8*)&Ab[row * 32 + s8];
      a[i][1] = *(const bf16x8*)&Ab[(128 + row) * 32 + s8];
    }
    if (t + 2 < NT) stageB(t + 2, 0);
    asm volatile("s_barrier" ::: "memory");
    __builtin_amdgcn_s_setprio(1);
#pragma unroll
    for (int i = 0; i < 4; ++i)
#pragma unroll
      for (int j = 0; j < 2; ++j)
#pragma unroll
        for (int ks = 0; ks < 2; ++ks)
          acc[4 + i][j] = MFMA(a[i][ks], b[j][ks], acc[4 + i][j]);
    __builtin_amdgcn_s_setprio(0);
    asm volatile("s_barrier" ::: "memory");

    // ---- phase 3: no reads; stage B(t+2) half1; counted wait; MFMA (i4-7, j2-3)
    if (t + 2 < NT) {
      stageB(t + 2, 1);
      asm volatile("s_waitcnt vmcnt(4)\n\ts_barrier" ::: "memory");
    } else {
      asm volatile("s_waitcnt vmcnt(0)\n\ts_barrier" ::: "memory");
    }
    __builtin_amdgcn_s_setprio(1);
#pragma unroll
    for (int i = 0; i < 4; ++i)
#pragma unroll
      for (int j = 2; j < 4; ++j)
#pragma unroll
        for (int ks = 0; ks < 2; ++ks)
          acc[4 + i][j] = MFMA(a[i][ks], b[j][ks], acc[4 + i][j]);
    __builtin_amdgcn_s_setprio(0);
    asm volatile("s_barrier" ::: "memory");
  }

  // epilogue: C/D layout col=lane&15, row=(lane>>4)*4+reg
#pragma unroll
  for (int i = 0; i < 8; ++i) {
    const int rowb = m0 + wr * 128 + i * 16 + q4 * 4;
#pragma unroll
    for (int j = 0; j < 4; ++j) {
      const int col = n0 + wc * 64 + j * 16 + l16;
      const float bv = BIAS ? bias[col] : 0.0f;
#pragma unroll
      for (int r = 0; r < 4; ++r)
        Cout[(size_t)(rowb + r) * NOUT + col] = (OutT)(acc[i][j][r] + bv);
    }
  }
}

// One block per (b,h,w) window. 4 waves x 64 q-rows, q-groups of 16 rows.
// SWAPPED-OPERAND flash attention (see r2). ROUND-9 change: K+freqs staging is now
// COALESCED — 8 consecutive lanes cover one row's full 128B (2 fully-used cache
// lines) instead of 64 lanes touching 64 distinct 6KB-strided lines at 16/64B used.
// New K layout k8[tok][slot]*16B with slot = db ^ (tok&7):
//   write: 64 lanes hit 64 distinct 16B chunks (2 lanes/bank) — conflict-free;
//   QK read bank-start = 4*((q4+4s)^(l16&7)) -> 8 lanes/bank-quad = wave64 minimum
//   (same conflict level as the old [dblk][tok] layout, verified).
// V keeps the old lane mapping (its scatter is conflict-checked in that order).
__global__ __launch_bounds__(256) void attn_win(const bf16* __restrict__ qkv,
                                                const bf16* __restrict__ freqs,
                                                bf16* __restrict__ ob) {
  __shared__ unsigned short k8[128 * 8 * 8];  // [tok][slot^][8]  16 KB (roped K)
  __shared__ unsigned short v8[16 * 64 * 8];  // [tokblk][d^swz][8] 16 KB (V^T)
  __shared__ unsigned short pT[4][16 * 128];  // per wave [q:16][tok:128] 4 KB

  const int bid = blockIdx.x;
  const int w = bid & 15, h = (bid >> 4) & 15, b = bid >> 8;
  const int n0 = w * 256;
  const int tid = threadIdx.x;
  const int wave = tid >> 6, lane = tid & 63;
  const int q4 = lane >> 4, l16 = lane & 15;
  const float scale = 0.125f;  // D^-0.5
  const int swz = (l16 & 7) << 4;  // byte XOR for pT (bits 4-6)
  const int kx = l16 & 7;          // k8 read slot XOR
  char* const pw = (char*)&pT[wave][0];

  // q fragments with rope, hoisted (B-frag: col=l16=q, k=(q4)*8+e, s picks d-half)
  bf16x8 qf[4][2];
#pragma unroll
  for (int g = 0; g < 4; ++g) {
    const int n = n0 + wave * 64 + g * 16 + l16;
    const bf16* qrow = qkv + (size_t)(b * kN + n) * kQKVN + h * kD;
    const bf16* frow = freqs + (size_t)n * kD;
#pragma unroll
    for (int s = 0; s < 2; ++s) {
      const int d0 = s * 32 + q4 * 8;
      qf[g][s] = rope8(*(const bf16x8*)(qrow + d0), *(const bf16x8*)(frow + d0));
    }
  }

  f32x4 O[4][4] = {};       // [group][d-tile]; rows q=q4*4+r, cols d=l16+16*jd
  float mrow[4], lrow[4];   // per-lane stats for q = g*16 + l16
#pragma unroll
  for (int g = 0; g < 4; ++g) { mrow[g] = -3.0e38f; lrow[g] = 0.0f; }

  for (int c = 0; c < 2; ++c) {
    const int nc = n0 + c * 128;
    __syncthreads();  // previous chunk's reads done before restaging
#pragma unroll
    for (int i = 0; i < 4; ++i) {
      const int cid = i * 256 + tid;
      // ---- K + freqs: coalesced (8 lanes = one token row's 128B, contiguous)
      {
        const int tok = cid >> 3, db = cid & 7;
        const int n = nc + tok;
        const size_t base = (size_t)(b * kN + n) * kQKVN + h * kD + db * 8;
        bf16x8 kv = *(const bf16x8*)(qkv + base + kC);
        bf16x8 fv = *(const bf16x8*)(freqs + (size_t)n * kD + db * 8);
        *(bf16x8*)&k8[(tok * 8 + (db ^ (tok & 7))) * 8] = rope8(kv, fv);
      }
      // ---- V: original lane mapping (scatter bank-pattern preserved)
      {
        const int tok = cid & 127, db = cid >> 7;
        const int n = nc + tok;
        const size_t base = (size_t)(b * kN + n) * kQKVN + h * kD + db * 8;
        bf16x8 vv = *(const bf16x8*)(qkv + base + 2 * kC);
        const int tb = tok >> 3, sl = tok & 7;
#pragma unroll
        for (int e = 0; e < 8; ++e) {
          const int d = db * 8 + e;
          ((bf16*)v8)[((tb * 64) + (d ^ (tb & 7))) * 8 + sl] = vv[e];
        }
      }
    }
    __syncthreads();

#pragma unroll
    for (int g = 0; g < 4; ++g) {
      // S^T = K Q^T over d=64: lane holds toks {j*16 + q4*4 + r} for q = g*16+l16
      f32x4 S[8] = {};
#pragma unroll
      for (int j = 0; j < 8; ++j)
#pragma unroll
        for (int s = 0; s < 2; ++s) {
          const int tok = j * 16 + l16;
          bf16x8 kf = *(const bf16x8*)&k8[(tok * 8 + ((q4 + 4 * s) ^ kx)) * 8];
          S[j] = MFMA(kf, qf[g][s], S[j]);  // swapped operands
        }
      // scale + in-lane max over 32 tokens (4 parallel chains), then cross-q4
      float m0_ = -3.0e38f, m1_ = -3.0e38f, m2_ = -3.0e38f, m3_ = -3.0e38f;
#pragma unroll
      for (int j = 0; j < 8; ++j) {
        S[j][0] *= scale; S[j][1] *= scale; S[j][2] *= scale; S[j][3] *= scale;
        m0_ = fmaxf(m0_, S[j][0]); m1_ = fmaxf(m1_, S[j][1]);
        m2_ = fmaxf(m2_, S[j][2]); m3_ = fmaxf(m3_, S[j][3]);
      }
      float mx = fmaxf(fmaxf(m0_, m1_), fmaxf(m2_, m3_));
      mx = fmaxf(mx, __shfl_xor(mx, 16));
      mx = fmaxf(mx, __shfl_xor(mx, 32));
      const float mnew = fmaxf(mrow[g], mx);
      const float al = __expf(mrow[g] - mnew);
      mrow[g] = mnew;
      float s0 = 0.f, s1 = 0.f, s2 = 0.f, s3 = 0.f;
#pragma unroll
      for (int j = 0; j < 8; ++j) {
        S[j][0] = __expf(S[j][0] - mnew); s0 += S[j][0];
        S[j][1] = __expf(S[j][1] - mnew); s1 += S[j][1];
        S[j][2] = __expf(S[j][2] - mnew); s2 += S[j][2];
        S[j][3] = __expf(S[j][3] - mnew); s3 += S[j][3];
      }
      float sm = (s0 + s1) + (s2 + s3);
      sm += __shfl_xor(sm, 16);
      sm += __shfl_xor(sm, 32);
      lrow[g] = lrow[g] * al + sm;
      // redistribute alpha to O-row owners (O rows are q = q4*4+r; al lives at lane l16=q)
      float alr[4];
#pragma unroll
      for (int r = 0; r < 4; ++r) alr[r] = __shfl(al, q4 * 4 + r);
#pragma unroll
      for (int jd = 0; jd < 4; ++jd)
#pragma unroll
        for (int r = 0; r < 4; ++r) O[g][jd][r] *= alr[r];
      // P writes: 8 x b64, layout pT[q=l16][tok], swizzled; lane's 4 r = 4 consecutive toks
#pragma unroll
      for (int j = 0; j < 8; ++j) {
        bf16x4 pk = {(bf16)S[j][0], (bf16)S[j][1], (bf16)S[j][2], (bf16)S[j][3]};
        *(bf16x4*)(pw + l16 * 256 + ((j * 32 + q4 * 8) ^ swz)) = pk;
      }
      asm volatile("s_waitcnt lgkmcnt(0)" ::: "memory");  // P writes visible (same wave)
      // O += P V: pf = A-frag [row=q=l16][k=tok=s4*32+q4*8+e] via swizzled b128
#pragma unroll
      for (int s4 = 0; s4 < 4; ++s4) {
        bf16x8 pf = *(const bf16x8*)(pw + l16 * 256 + ((s4 * 64 + q4 * 16) ^ swz));
        const int tb2 = q4 + 4 * s4;
#pragma unroll
        for (int jd = 0; jd < 4; ++jd) {
          const int d2 = (l16 + 16 * jd) ^ (tb2 & 7);
          bf16x8 vf = *(const bf16x8*)&v8[(tb2 * 64 + d2) * 8];
          O[g][jd] = MFMA(pf, vf, O[g][jd]);
        }
      }
      asm volatile("" ::: "memory");  // keep next g's pT writes after this g's reads
    }
  }

  // epilogue: normalize (lrow lives at lane l16=q; O rows are q=q4*4+r), write bf16
#pragma unroll
  for (int g = 0; g < 4; ++g) {
    float lr[4];
#pragma unroll
    for (int r = 0; r < 4; ++r) lr[r] = __shfl(lrow[g], q4 * 4 + r);
    const int nb = n0 + wave * 64 + g * 16 + q4 * 4;
#pragma unroll
    for (int jd = 0; jd < 4; ++jd) {
      const int d = l16 + 16 * jd;
#pragma unroll
      for (int r = 0; r < 4; ++r) {
        const float v = O[g][jd][r] / lr[r];
        ob[(size_t)(b * kN + nb + r) * kC + h * kD + d] = (bf16)v;
      }
    }
  }
}

extern "C" void kernel_launch(void* const* d_in, const int* in_sizes, int n_in,
                              void* d_out, int out_size, void* d_ws, size_t ws_size,
                              hipStream_t stream) {
  (void)in_sizes; (void)n_in; (void)out_size; (void)ws_size;
  const float* x      = (const float*)d_in[0];
  const float* freqs  = (const float*)d_in[1];
  const float* qkv_w  = (const float*)d_in[2];
  const float* proj_w = (const float*)d_in[3];
  const float* proj_b = (const float*)d_in[4];
  float* out = (float*)d_out;

  // workspace layout (bf16 elems):
  //  [qkv_buf: kM*kQKVN][shared: kM*kC (x_bf16 then attn_buf)][qkvw][projw][freqs]
  bf16* qkv_buf = (bf16*)d_ws;
  bf16* shared  = qkv_buf + (size_t)kM * kQKVN;
  bf16* x_b     = shared;                     // live: convert -> gemm1
  bf16* attn_b  = shared;                     // live: attn -> gemm2
  bf16* qkvw_b  = shared + (size_t)kM * kC;
  bf16* projw_b = qkvw_b + (size_t)kQKVN * kC;
  bf16* freqs_b = projw_b + (size_t)kC * kC;

  // fp32 -> bf16 conversions
  cvt_bf16<<<(kM * kC / 4 + 255) / 256, 256, 0, stream>>>(x, x_b, kM * kC / 4);
  cvt_bf16<<<(kQKVN * kC / 4 + 255) / 256, 256, 0, stream>>>(qkv_w, qkvw_b, kQKVN * kC / 4);
  cvt_bf16<<<(kC * kC / 4 + 255) / 256, 256, 0, stream>>>(proj_w, projw_b, kC * kC / 4);
  cvt_bf16<<<(kN * kD / 4 + 255) / 256, 256, 0, stream>>>(freqs, freqs_b, kN * kD / 4);

  // QKV GEMM as three per-slab dispatches (256 blocks each = exactly 1/CU):
  // surfaces attn/proj in the profiler top-5 while keeping total block count.
  for (int d = 0; d < 3; ++d)
    gemm_bt<kQKVN, false, bf16><<<dim3(kC / 256, kM / 256), 512, 0, stream>>>(
        x_b, qkvw_b + (size_t)d * kC * kK, nullptr, qkv_buf + d * kC);
  attn_win<<<dim3(kB * kH * (kN / 256)), 256, 0, stream>>>(qkv_buf, freqs_b, attn_b);
  gemm_bt<kC, true, float><<<dim3(kC / 256, kM / 256), 512, 0, stream>>>(
      attn_b, projw_b, proj_b, out);
}